// Round 1
// baseline (345.010 us; speedup 1.0000x reference)
//
#include <hip/hip_runtime.h>
#include <hip/hip_bf16.h>

#define IN_F  128
#define HID_F 256
#define OUT_F 64
#define BUCKET_SHIFT 9
#define BUCKET_SZ 512
#define EPB 8192            // edges per binning block

typedef __attribute__((ext_vector_type(8))) short bf16x8;
typedef __attribute__((ext_vector_type(4))) float f32x4;

__device__ __forceinline__ float bf2f(unsigned short u) {
    union { unsigned int i; float f; } v; v.i = ((unsigned int)u) << 16; return v.f;
}
__device__ __forceinline__ float bf2f_lo(unsigned int p) {
    union { unsigned int i; float f; } v; v.i = p << 16; return v.f;
}
__device__ __forceinline__ float bf2f_hi(unsigned int p) {
    union { unsigned int i; float f; } v; v.i = p & 0xffff0000u; return v.f;
}
__device__ __forceinline__ unsigned short f2bf(float f) {
    __hip_bfloat16 b = __float2bfloat16(f);
    return *reinterpret_cast<unsigned short*>(&b);
}

// ---- x fp32 -> bf16 (8 elems/thread) ------------------------------------
__global__ __launch_bounds__(256) void k_xconv(
    const float* __restrict__ x, unsigned short* __restrict__ xb, long long total8)
{
    long long i = (long long)blockIdx.x * blockDim.x + threadIdx.x;
    if (i >= total8) return;
    const float4* p = reinterpret_cast<const float4*>(x) + i * 2;
    float4 a = p[0], b = p[1];
    ushort4 o0, o1;
    o0.x = f2bf(a.x); o0.y = f2bf(a.y); o0.z = f2bf(a.z); o0.w = f2bf(a.w);
    o1.x = f2bf(b.x); o1.y = f2bf(b.y); o1.z = f2bf(b.z); o1.w = f2bf(b.w);
    reinterpret_cast<ushort4*>(xb)[i * 2]     = o0;
    reinterpret_cast<ushort4*>(xb)[i * 2 + 1] = o1;
}

// ---- CSR build via bucketed multisplit (no global per-edge atomics) -----
// Phase 1: per-block LDS histogram over buckets -> counts[b*A + i]
__global__ __launch_bounds__(256) void k_hist(
    const int* __restrict__ dst, int* __restrict__ counts,
    int nEdges, int NB)
{
    __shared__ int hist[256];
    int t = threadIdx.x;
    hist[t] = 0;
    __syncthreads();
    long long base = (long long)blockIdx.x * EPB;
    #pragma unroll
    for (int k = 0; k < EPB / 256; ++k) {
        long long e = base + k * 256 + t;
        if (e < nEdges) atomicAdd(&hist[dst[e] >> BUCKET_SHIFT], 1);
    }
    __syncthreads();
    if (t < NB) counts[t * gridDim.x + blockIdx.x] = hist[t];
}

// Phase 2a: bucket totals (NB blocks, parallel reduce over A counts each).
__global__ __launch_bounds__(256) void k_btot(
    const int* __restrict__ counts, int* __restrict__ btot, int A)
{
    __shared__ int sh[256];
    int b = blockIdx.x, t = threadIdx.x;
    int s = 0;
    for (int i = t; i < A; i += 256) s += counts[(size_t)b * A + i];
    sh[t] = s; __syncthreads();
    for (int d = 128; d > 0; d >>= 1) {
        if (t < d) sh[t] += sh[t + d];
        __syncthreads();
    }
    if (t == 0) btot[b] = sh[0];
}

// Phase 2b: one block scans NB totals -> bucketBase (exclusive).
__global__ __launch_bounds__(256) void k_scanNB(
    const int* __restrict__ btot, int* __restrict__ bucketBase,
    int* __restrict__ rowptr, int NB, int nNodes, int nEdges)
{
    __shared__ int sh[256];
    int t = threadIdx.x;
    int v = (t < NB) ? btot[t] : 0;
    sh[t] = v; __syncthreads();
    for (int d = 1; d < 256; d <<= 1) {
        int add = (t >= d) ? sh[t - d] : 0;
        __syncthreads();
        sh[t] += add;
        __syncthreads();
    }
    if (t < NB) bucketBase[t] = sh[t] - v;
    if (t == 0) { bucketBase[NB] = nEdges; rowptr[nNodes] = nEdges; }
}

// Phase 2c: per-bucket exclusive scan of its A counts + base -> start cursors.
__global__ __launch_bounds__(256) void k_cursor(
    int* __restrict__ counts, const int* __restrict__ bucketBase, int A)
{
    __shared__ int sh[256];
    int b = blockIdx.x, t = threadIdx.x;
    int run = bucketBase[b];
    for (int base = 0; base < A; base += 256) {
        int idx = base + t;
        int v = (idx < A) ? counts[(size_t)b * A + idx] : 0;
        sh[t] = v; __syncthreads();
        for (int d = 1; d < 256; d <<= 1) {
            int add = (t >= d) ? sh[t - d] : 0;
            __syncthreads();
            sh[t] += add;
            __syncthreads();
        }
        if (idx < A) counts[(size_t)b * A + idx] = run + sh[t] - v;
        run += sh[255];
        __syncthreads();
    }
}

// Phase 3: place (src,dst) pairs into bucket-contiguous binned[] (8B stores).
__global__ __launch_bounds__(256) void k_bin(
    const int* __restrict__ src, const int* __restrict__ dst,
    const int* __restrict__ counts, unsigned long long* __restrict__ binned,
    int nEdges, int NB)
{
    __shared__ int cur[256];
    int t = threadIdx.x;
    if (t < NB) cur[t] = counts[t * gridDim.x + blockIdx.x];
    __syncthreads();
    long long base = (long long)blockIdx.x * EPB;
    #pragma unroll
    for (int k = 0; k < EPB / 256; ++k) {
        long long e = base + k * 256 + t;
        if (e < nEdges) {
            int s = src[e], d = dst[e];
            int pos = atomicAdd(&cur[d >> BUCKET_SHIFT], 1);
            binned[pos] = (((unsigned long long)(unsigned)d) << 32) | (unsigned)s;
        }
    }
}

// Phase 4: per-bucket local CSR: LDS deg hist -> LDS scan -> rowptr + eidx.
__global__ __launch_bounds__(256) void k_localcsr(
    const unsigned long long* __restrict__ binned, const int* __restrict__ bucketBase,
    int* __restrict__ rowptr, int* __restrict__ eidx, int nNodes)
{
    __shared__ int ldeg[BUCKET_SZ];
    __shared__ int lscan[256];
    int t = threadIdx.x;
    ldeg[t] = 0; ldeg[t + 256] = 0;
    __syncthreads();
    int eb0 = bucketBase[blockIdx.x], eb1 = bucketBase[blockIdx.x + 1];
    int node0 = blockIdx.x << BUCKET_SHIFT;
    for (int e = eb0 + t; e < eb1; e += 256) {
        int d = (int)(binned[e] >> 32);
        atomicAdd(&ldeg[d - node0], 1);
    }
    __syncthreads();
    int d0 = ldeg[2 * t], d1 = ldeg[2 * t + 1];
    int s = d0 + d1;
    lscan[t] = s;
    __syncthreads();
    for (int d = 1; d < 256; d <<= 1) {
        int add = (t >= d) ? lscan[t - d] : 0;
        __syncthreads();
        lscan[t] += add;
        __syncthreads();
    }
    int excl = lscan[t] - s;
    ldeg[2 * t]     = excl;        // becomes local cursor
    ldeg[2 * t + 1] = excl + d0;
    int n0 = node0 + 2 * t;
    if (n0 < nNodes)     rowptr[n0]     = eb0 + excl;
    if (n0 + 1 < nNodes) rowptr[n0 + 1] = eb0 + excl + d0;
    __syncthreads();
    for (int e = eb0 + t; e < eb1; e += 256) {
        unsigned long long p = binned[e];
        int d = (int)(p >> 32), sv = (int)(p & 0xffffffffu);
        int pos = atomicAdd(&ldeg[d - node0], 1);
        eidx[eb0 + pos] = sv;
    }
}

// ---- Weight swizzle: fp32 W -> bf16 in B-fragment order -----------------
__global__ __launch_bounds__(256) void k_wconv(
    const float* __restrict__ W1, const float* __restrict__ W2,
    unsigned short* __restrict__ w1s, unsigned short* __restrict__ w2s)
{
    int idx = blockIdx.x * blockDim.x + threadIdx.x;
    if (idx < IN_F * HID_F) {            // W1: 16 ntiles x 4 ksteps
        int c = idx >> 9, L = (idx >> 3) & 63, j = idx & 7;
        int ntile = c >> 2, kstep = c & 3;
        int k = kstep * 32 + (L >> 4) * 8 + j;
        int n = ntile * 16 + (L & 15);
        w1s[idx] = f2bf(W1[k * HID_F + n]);
    }
    if (idx < HID_F * OUT_F) {           // W2: 4 ntiles x 8 ksteps
        int c = idx >> 9, L = (idx >> 3) & 63, j = idx & 7;
        int ntile = c >> 3, kstep = c & 7;
        int k = kstep * 32 + (L >> 4) * 8 + j;
        int n = ntile * 16 + (L & 15);
        w2s[idx] = f2bf(W2[k * OUT_F + n]);
    }
}

// ---- Layer-1 gather: agg[n] = xb[n] + sum xb[src] -----------------------
// Scalarized addressing: n/beg/end forced uniform (readfirstlane), src
// indices extracted with v_readlane -> SGPR row base -> saddr loads.
// Removes per-edge ds_bpermute + per-lane 64-bit VALU address math.
__global__ __launch_bounds__(256) void gather1(
    const unsigned short* __restrict__ xb, const int* __restrict__ rowptr,
    const int* __restrict__ eidx, unsigned short* __restrict__ agg, int nNodes)
{
    int n    = blockIdx.x * 4 + __builtin_amdgcn_readfirstlane(threadIdx.x >> 6);
    int lane = threadIdx.x & 63;
    if (n >= nNodes) return;
    int beg = __builtin_amdgcn_readfirstlane(rowptr[n]);
    int end = __builtin_amdgcn_readfirstlane(rowptr[n + 1]);
    const size_t lane2 = (size_t)(lane * 2);
    unsigned int self = *reinterpret_cast<const unsigned int*>(
        xb + (size_t)n * IN_F + lane2);
    float ax = bf2f_lo(self), ay = bf2f_hi(self);
    for (int base = beg; base < end; base += 64) {
        int cnt = min(64, end - base);
        int e = (base + lane < end) ? eidx[base + lane] : 0;
        int i = 0;
        for (; i + 4 <= cnt; i += 4) {
            int s0 = __builtin_amdgcn_readlane(e, i);
            int s1 = __builtin_amdgcn_readlane(e, i + 1);
            int s2 = __builtin_amdgcn_readlane(e, i + 2);
            int s3 = __builtin_amdgcn_readlane(e, i + 3);
            unsigned int v0 = *reinterpret_cast<const unsigned int*>(xb + (size_t)s0 * IN_F + lane2);
            unsigned int v1 = *reinterpret_cast<const unsigned int*>(xb + (size_t)s1 * IN_F + lane2);
            unsigned int v2 = *reinterpret_cast<const unsigned int*>(xb + (size_t)s2 * IN_F + lane2);
            unsigned int v3 = *reinterpret_cast<const unsigned int*>(xb + (size_t)s3 * IN_F + lane2);
            ax += bf2f_lo(v0) + bf2f_lo(v1) + bf2f_lo(v2) + bf2f_lo(v3);
            ay += bf2f_hi(v0) + bf2f_hi(v1) + bf2f_hi(v2) + bf2f_hi(v3);
        }
        for (; i < cnt; ++i) {
            int s = __builtin_amdgcn_readlane(e, i);
            unsigned int v = *reinterpret_cast<const unsigned int*>(xb + (size_t)s * IN_F + lane2);
            ax += bf2f_lo(v); ay += bf2f_hi(v);
        }
    }
    unsigned int p = (unsigned int)f2bf(ax) | ((unsigned int)f2bf(ay) << 16);
    *reinterpret_cast<unsigned int*>(agg + (size_t)n * IN_F + lane2) = p;
}

// ---- GEMM1 (MFMA): h1[M,256] = agg[M,128] @ W1, bf16 out ----------------
__global__ __launch_bounds__(256) void gemm1_mfma(
    const unsigned short* __restrict__ agg, const unsigned short* __restrict__ w1s,
    unsigned short* __restrict__ h1, int nNodes)
{
    int wave = threadIdx.x >> 6, lane = threadIdx.x & 63;
    int m0 = blockIdx.x * 64 + wave * 16;
    if (m0 >= nNodes) return;
    int row = lane & 15, quad = lane >> 4;
    f32x4 acc[16] = {};
    const bf16x8* aBase = reinterpret_cast<const bf16x8*>(
        agg + (size_t)(m0 + row) * IN_F + quad * 8);
    const bf16x8* bBase = reinterpret_cast<const bf16x8*>(w1s) + lane;
    #pragma unroll
    for (int ks = 0; ks < 4; ++ks) {
        bf16x8 a = aBase[ks * 4];
        #pragma unroll
        for (int nt = 0; nt < 16; ++nt) {
            bf16x8 b = bBase[(nt * 4 + ks) * 64];
            acc[nt] = __builtin_amdgcn_mfma_f32_16x16x32_bf16(a, b, acc[nt], 0, 0, 0);
        }
    }
    size_t outBase = (size_t)(m0 + quad * 4) * HID_F + row;
    #pragma unroll
    for (int i = 0; i < 4; ++i) {
        if (m0 + quad * 4 + i >= nNodes) break;   // tail guard
        #pragma unroll
        for (int nt = 0; nt < 16; ++nt)
            h1[outBase + (size_t)i * HID_F + nt * 16] = f2bf(acc[nt][i]);
    }
}

// ---- GEMM2 (MFMA): z[M,64] = h1[M,256] @ W2, bf16 out -------------------
__global__ __launch_bounds__(256) void gemm2_mfma(
    const unsigned short* __restrict__ h1, const unsigned short* __restrict__ w2s,
    unsigned short* __restrict__ z, int nNodes)
{
    int wave = threadIdx.x >> 6, lane = threadIdx.x & 63;
    int m0 = blockIdx.x * 64 + wave * 16;
    if (m0 >= nNodes) return;
    int row = lane & 15, quad = lane >> 4;
    f32x4 acc[4] = {};
    const bf16x8* aBase = reinterpret_cast<const bf16x8*>(
        h1 + (size_t)(m0 + row) * HID_F + quad * 8);
    const bf16x8* bBase = reinterpret_cast<const bf16x8*>(w2s) + lane;
    #pragma unroll
    for (int ks = 0; ks < 8; ++ks) {
        bf16x8 a = aBase[ks * 4];
        #pragma unroll
        for (int nt = 0; nt < 4; ++nt) {
            bf16x8 b = bBase[(nt * 8 + ks) * 64];
            acc[nt] = __builtin_amdgcn_mfma_f32_16x16x32_bf16(a, b, acc[nt], 0, 0, 0);
        }
    }
    size_t outBase = (size_t)(m0 + quad * 4) * OUT_F + row;
    #pragma unroll
    for (int i = 0; i < 4; ++i) {
        if (m0 + quad * 4 + i >= nNodes) break;   // tail guard
        #pragma unroll
        for (int nt = 0; nt < 4; ++nt)
            z[outBase + (size_t)i * OUT_F + nt * 16] = f2bf(acc[nt][i]);
    }
}

// ---- Layer-2 gather (commuted): out[n] = z[n] + sum z[src] --------------
// Same scalarized-addressing treatment as gather1.
__global__ __launch_bounds__(256) void gather2(
    const unsigned short* __restrict__ z, const int* __restrict__ rowptr,
    const int* __restrict__ eidx, float* __restrict__ out, int nNodes)
{
    int n    = blockIdx.x * 4 + __builtin_amdgcn_readfirstlane(threadIdx.x >> 6);
    int lane = threadIdx.x & 63;
    if (n >= nNodes) return;
    int beg = __builtin_amdgcn_readfirstlane(rowptr[n]);
    int end = __builtin_amdgcn_readfirstlane(rowptr[n + 1]);
    float acc = bf2f(z[(size_t)n * OUT_F + lane]);
    for (int base = beg; base < end; base += 64) {
        int cnt = min(64, end - base);
        int e = (base + lane < end) ? eidx[base + lane] : 0;
        int i = 0;
        for (; i + 4 <= cnt; i += 4) {
            int s0 = __builtin_amdgcn_readlane(e, i);
            int s1 = __builtin_amdgcn_readlane(e, i + 1);
            int s2 = __builtin_amdgcn_readlane(e, i + 2);
            int s3 = __builtin_amdgcn_readlane(e, i + 3);
            unsigned short v0 = z[(size_t)s0 * OUT_F + lane];
            unsigned short v1 = z[(size_t)s1 * OUT_F + lane];
            unsigned short v2 = z[(size_t)s2 * OUT_F + lane];
            unsigned short v3 = z[(size_t)s3 * OUT_F + lane];
            acc += bf2f(v0) + bf2f(v1) + bf2f(v2) + bf2f(v3);
        }
        for (; i < cnt; ++i) {
            int s = __builtin_amdgcn_readlane(e, i);
            acc += bf2f(z[(size_t)s * OUT_F + lane]);
        }
    }
    out[(size_t)n * OUT_F + lane] = acc;
}

extern "C" void kernel_launch(void* const* d_in, const int* in_sizes, int n_in,
                              void* d_out, int out_size, void* d_ws, size_t ws_size,
                              hipStream_t stream) {
    const float* x  = (const float*)d_in[0];
    const int* esrc = (const int*)d_in[1];
    const int* edst = (const int*)d_in[2];
    const float* W1 = (const float*)d_in[3];
    const float* W2 = (const float*)d_in[4];
    float* out      = (float*)d_out;

    const int nNodes = in_sizes[0] / IN_F;
    const int nEdges = in_sizes[1];
    const int NB = (nNodes + BUCKET_SZ - 1) / BUCKET_SZ;   // 196 (must be <= 256)
    const int A  = (nEdges + EPB - 1) / EPB;               // 196 binning blocks

    // Workspace (~96.7 MB; 110.4 MB known-safe from R3):
    char* ws = (char*)d_ws;
    const size_t h1_b     = (size_t)nNodes * HID_F * sizeof(unsigned short);
    const size_t aggz_b   = (size_t)nNodes * IN_F * sizeof(unsigned short);
    const size_t binned_b = (size_t)nEdges * sizeof(unsigned long long);
    const size_t eidx_b   = (size_t)nEdges * sizeof(int);
    unsigned short* h1  = (unsigned short*)ws;
    unsigned short* xb  = (unsigned short*)ws;                   // alias of h1
    unsigned short* agg = (unsigned short*)(ws + h1_b);
    unsigned short* z   = (unsigned short*)(ws + h1_b);          // alias of agg
    unsigned long long* binned = (unsigned long long*)(ws + h1_b + aggz_b);
    int* eidx           = (int*)(ws + h1_b + aggz_b + binned_b);
    unsigned short* w1s = (unsigned short*)(ws + h1_b + aggz_b + binned_b + eidx_b);
    unsigned short* w2s = w1s + IN_F * HID_F;
    int* rowptr     = (int*)(w2s + HID_F * OUT_F);
    int* counts     = rowptr + (nNodes + 1);
    int* bucketBase = counts + (size_t)NB * A;
    int* btot       = bucketBase + (NB + 1);

    k_wconv<<<(IN_F * HID_F + 255) / 256, 256, 0, stream>>>(W1, W2, w1s, w2s);

    long long total8 = (long long)nNodes * IN_F / 8;
    k_xconv<<<(int)((total8 + 255) / 256), 256, 0, stream>>>(x, xb, total8);

    k_hist<<<A, 256, 0, stream>>>(edst, counts, nEdges, NB);
    k_btot<<<NB, 256, 0, stream>>>(counts, btot, A);
    k_scanNB<<<1, 256, 0, stream>>>(btot, bucketBase, rowptr, NB, nNodes, nEdges);
    k_cursor<<<NB, 256, 0, stream>>>(counts, bucketBase, A);
    k_bin<<<A, 256, 0, stream>>>(esrc, edst, counts, binned, nEdges, NB);
    k_localcsr<<<NB, 256, 0, stream>>>(binned, bucketBase, rowptr, eidx, nNodes);

    const int nBlocks = (nNodes + 3) / 4;
    const int mBlocks = (nNodes + 63) / 64;
    gather1<<<nBlocks, 256, 0, stream>>>(xb, rowptr, eidx, agg, nNodes);
    gemm1_mfma<<<mBlocks, 256, 0, stream>>>(agg, w1s, h1, nNodes);
    gemm2_mfma<<<mBlocks, 256, 0, stream>>>(h1, w2s, z, nNodes);
    gather2<<<nBlocks, 256, 0, stream>>>(z, rowptr, eidx, out, nNodes);
}

// Round 2
// 332.933 us; speedup vs baseline: 1.0363x; 1.0363x over previous
//
#include <hip/hip_runtime.h>
#include <hip/hip_bf16.h>

#define IN_F  128
#define HID_F 256
#define OUT_F 64
#define BUCKET_SHIFT 9
#define BUCKET_SZ 512
#define EPB 8192            // edges per binning block

typedef __attribute__((ext_vector_type(8))) short bf16x8;
typedef __attribute__((ext_vector_type(4))) float f32x4;

__device__ __forceinline__ float bf2f(unsigned short u) {
    union { unsigned int i; float f; } v; v.i = ((unsigned int)u) << 16; return v.f;
}
__device__ __forceinline__ float bf2f_lo(unsigned int p) {
    union { unsigned int i; float f; } v; v.i = p << 16; return v.f;
}
__device__ __forceinline__ float bf2f_hi(unsigned int p) {
    union { unsigned int i; float f; } v; v.i = p & 0xffff0000u; return v.f;
}
__device__ __forceinline__ unsigned short f2bf(float f) {
    __hip_bfloat16 b = __float2bfloat16(f);
    return *reinterpret_cast<unsigned short*>(&b);
}

// ---- x fp32 -> bf16 (8 elems/thread) ------------------------------------
__global__ __launch_bounds__(256) void k_xconv(
    const float* __restrict__ x, unsigned short* __restrict__ xb, long long total8)
{
    long long i = (long long)blockIdx.x * blockDim.x + threadIdx.x;
    if (i >= total8) return;
    const float4* p = reinterpret_cast<const float4*>(x) + i * 2;
    float4 a = p[0], b = p[1];
    ushort4 o0, o1;
    o0.x = f2bf(a.x); o0.y = f2bf(a.y); o0.z = f2bf(a.z); o0.w = f2bf(a.w);
    o1.x = f2bf(b.x); o1.y = f2bf(b.y); o1.z = f2bf(b.z); o1.w = f2bf(b.w);
    reinterpret_cast<ushort4*>(xb)[i * 2]     = o0;
    reinterpret_cast<ushort4*>(xb)[i * 2 + 1] = o1;
}

// ---- CSR build via bucketed multisplit (no global per-edge atomics) -----
// Phase 1: per-block LDS histogram over buckets -> counts[b*A + i]
__global__ __launch_bounds__(256) void k_hist(
    const int* __restrict__ dst, int* __restrict__ counts,
    int nEdges, int NB)
{
    __shared__ int hist[256];
    int t = threadIdx.x;
    hist[t] = 0;
    __syncthreads();
    long long base = (long long)blockIdx.x * EPB;
    #pragma unroll
    for (int k = 0; k < EPB / 256; ++k) {
        long long e = base + k * 256 + t;
        if (e < nEdges) atomicAdd(&hist[dst[e] >> BUCKET_SHIFT], 1);
    }
    __syncthreads();
    if (t < NB) counts[t * gridDim.x + blockIdx.x] = hist[t];
}

// Phase 2a: bucket totals (NB blocks, parallel reduce over A counts each).
__global__ __launch_bounds__(256) void k_btot(
    const int* __restrict__ counts, int* __restrict__ btot, int A)
{
    __shared__ int sh[256];
    int b = blockIdx.x, t = threadIdx.x;
    int s = 0;
    for (int i = t; i < A; i += 256) s += counts[(size_t)b * A + i];
    sh[t] = s; __syncthreads();
    for (int d = 128; d > 0; d >>= 1) {
        if (t < d) sh[t] += sh[t + d];
        __syncthreads();
    }
    if (t == 0) btot[b] = sh[0];
}

// Phase 2b: one block scans NB totals -> bucketBase (exclusive).
__global__ __launch_bounds__(256) void k_scanNB(
    const int* __restrict__ btot, int* __restrict__ bucketBase,
    int* __restrict__ rowptr, int NB, int nNodes, int nEdges)
{
    __shared__ int sh[256];
    int t = threadIdx.x;
    int v = (t < NB) ? btot[t] : 0;
    sh[t] = v; __syncthreads();
    for (int d = 1; d < 256; d <<= 1) {
        int add = (t >= d) ? sh[t - d] : 0;
        __syncthreads();
        sh[t] += add;
        __syncthreads();
    }
    if (t < NB) bucketBase[t] = sh[t] - v;
    if (t == 0) { bucketBase[NB] = nEdges; rowptr[nNodes] = nEdges; }
}

// Phase 2c: per-bucket exclusive scan of its A counts + base -> start cursors.
__global__ __launch_bounds__(256) void k_cursor(
    int* __restrict__ counts, const int* __restrict__ bucketBase, int A)
{
    __shared__ int sh[256];
    int b = blockIdx.x, t = threadIdx.x;
    int run = bucketBase[b];
    for (int base = 0; base < A; base += 256) {
        int idx = base + t;
        int v = (idx < A) ? counts[(size_t)b * A + idx] : 0;
        sh[t] = v; __syncthreads();
        for (int d = 1; d < 256; d <<= 1) {
            int add = (t >= d) ? sh[t - d] : 0;
            __syncthreads();
            sh[t] += add;
            __syncthreads();
        }
        if (idx < A) counts[(size_t)b * A + idx] = run + sh[t] - v;
        run += sh[255];
        __syncthreads();
    }
}

// Phase 3: place (src,dst) pairs into bucket-contiguous binned[] (8B stores).
__global__ __launch_bounds__(256) void k_bin(
    const int* __restrict__ src, const int* __restrict__ dst,
    const int* __restrict__ counts, unsigned long long* __restrict__ binned,
    int nEdges, int NB)
{
    __shared__ int cur[256];
    int t = threadIdx.x;
    if (t < NB) cur[t] = counts[t * gridDim.x + blockIdx.x];
    __syncthreads();
    long long base = (long long)blockIdx.x * EPB;
    #pragma unroll
    for (int k = 0; k < EPB / 256; ++k) {
        long long e = base + k * 256 + t;
        if (e < nEdges) {
            int s = src[e], d = dst[e];
            int pos = atomicAdd(&cur[d >> BUCKET_SHIFT], 1);
            binned[pos] = (((unsigned long long)(unsigned)d) << 32) | (unsigned)s;
        }
    }
}

// Phase 4: per-bucket local CSR: LDS deg hist -> LDS scan -> rowptr + eidx.
__global__ __launch_bounds__(256) void k_localcsr(
    const unsigned long long* __restrict__ binned, const int* __restrict__ bucketBase,
    int* __restrict__ rowptr, int* __restrict__ eidx, int nNodes)
{
    __shared__ int ldeg[BUCKET_SZ];
    __shared__ int lscan[256];
    int t = threadIdx.x;
    ldeg[t] = 0; ldeg[t + 256] = 0;
    __syncthreads();
    int eb0 = bucketBase[blockIdx.x], eb1 = bucketBase[blockIdx.x + 1];
    int node0 = blockIdx.x << BUCKET_SHIFT;
    for (int e = eb0 + t; e < eb1; e += 256) {
        int d = (int)(binned[e] >> 32);
        atomicAdd(&ldeg[d - node0], 1);
    }
    __syncthreads();
    int d0 = ldeg[2 * t], d1 = ldeg[2 * t + 1];
    int s = d0 + d1;
    lscan[t] = s;
    __syncthreads();
    for (int d = 1; d < 256; d <<= 1) {
        int add = (t >= d) ? lscan[t - d] : 0;
        __syncthreads();
        lscan[t] += add;
        __syncthreads();
    }
    int excl = lscan[t] - s;
    ldeg[2 * t]     = excl;        // becomes local cursor
    ldeg[2 * t + 1] = excl + d0;
    int n0 = node0 + 2 * t;
    if (n0 < nNodes)     rowptr[n0]     = eb0 + excl;
    if (n0 + 1 < nNodes) rowptr[n0 + 1] = eb0 + excl + d0;
    __syncthreads();
    for (int e = eb0 + t; e < eb1; e += 256) {
        unsigned long long p = binned[e];
        int d = (int)(p >> 32), sv = (int)(p & 0xffffffffu);
        int pos = atomicAdd(&ldeg[d - node0], 1);
        eidx[eb0 + pos] = sv;
    }
}

// ---- Weight swizzle: fp32 W -> bf16 in B-fragment order -----------------
__global__ __launch_bounds__(256) void k_wconv(
    const float* __restrict__ W1, const float* __restrict__ W2,
    unsigned short* __restrict__ w1s, unsigned short* __restrict__ w2s)
{
    int idx = blockIdx.x * blockDim.x + threadIdx.x;
    if (idx < IN_F * HID_F) {            // W1: 16 ntiles x 4 ksteps
        int c = idx >> 9, L = (idx >> 3) & 63, j = idx & 7;
        int ntile = c >> 2, kstep = c & 3;
        int k = kstep * 32 + (L >> 4) * 8 + j;
        int n = ntile * 16 + (L & 15);
        w1s[idx] = f2bf(W1[k * HID_F + n]);
    }
    if (idx < HID_F * OUT_F) {           // W2: 4 ntiles x 8 ksteps
        int c = idx >> 9, L = (idx >> 3) & 63, j = idx & 7;
        int ntile = c >> 3, kstep = c & 7;
        int k = kstep * 32 + (L >> 4) * 8 + j;
        int n = ntile * 16 + (L & 15);
        w2s[idx] = f2bf(W2[k * OUT_F + n]);
    }
}

// ---- Layer-1 gather: agg[n] = xb[n] + sum xb[src] -----------------------
// Scalarized addressing (saddr loads) + 16-deep edge unroll: 16 row loads
// (4 KB) in flight per wave before the first accumulate-wait. Avg degree is
// 16, so most nodes complete in one issue-burst -> one latency bubble/node.
__global__ __launch_bounds__(256) void gather1(
    const unsigned short* __restrict__ xb, const int* __restrict__ rowptr,
    const int* __restrict__ eidx, unsigned short* __restrict__ agg, int nNodes)
{
    int n    = blockIdx.x * 4 + __builtin_amdgcn_readfirstlane(threadIdx.x >> 6);
    int lane = threadIdx.x & 63;
    if (n >= nNodes) return;
    int beg = __builtin_amdgcn_readfirstlane(rowptr[n]);
    int end = __builtin_amdgcn_readfirstlane(rowptr[n + 1]);
    const size_t lane2 = (size_t)(lane * 2);
    unsigned int self = *reinterpret_cast<const unsigned int*>(
        xb + (size_t)n * IN_F + lane2);
    float ax = bf2f_lo(self), ay = bf2f_hi(self);
    for (int base = beg; base < end; base += 64) {
        int cnt = min(64, end - base);
        int e = (base + lane < end) ? eidx[base + lane] : 0;
        int i = 0;
        for (; i + 16 <= cnt; i += 16) {
            unsigned int v[16];
            #pragma unroll
            for (int j = 0; j < 16; ++j) {
                int s = __builtin_amdgcn_readlane(e, i + j);
                v[j] = *reinterpret_cast<const unsigned int*>(
                    xb + (size_t)s * IN_F + lane2);
            }
            #pragma unroll
            for (int j = 0; j < 16; ++j) {
                ax += bf2f_lo(v[j]); ay += bf2f_hi(v[j]);
            }
        }
        for (; i + 4 <= cnt; i += 4) {
            int s0 = __builtin_amdgcn_readlane(e, i);
            int s1 = __builtin_amdgcn_readlane(e, i + 1);
            int s2 = __builtin_amdgcn_readlane(e, i + 2);
            int s3 = __builtin_amdgcn_readlane(e, i + 3);
            unsigned int v0 = *reinterpret_cast<const unsigned int*>(xb + (size_t)s0 * IN_F + lane2);
            unsigned int v1 = *reinterpret_cast<const unsigned int*>(xb + (size_t)s1 * IN_F + lane2);
            unsigned int v2 = *reinterpret_cast<const unsigned int*>(xb + (size_t)s2 * IN_F + lane2);
            unsigned int v3 = *reinterpret_cast<const unsigned int*>(xb + (size_t)s3 * IN_F + lane2);
            ax += bf2f_lo(v0) + bf2f_lo(v1) + bf2f_lo(v2) + bf2f_lo(v3);
            ay += bf2f_hi(v0) + bf2f_hi(v1) + bf2f_hi(v2) + bf2f_hi(v3);
        }
        for (; i < cnt; ++i) {
            int s = __builtin_amdgcn_readlane(e, i);
            unsigned int v = *reinterpret_cast<const unsigned int*>(xb + (size_t)s * IN_F + lane2);
            ax += bf2f_lo(v); ay += bf2f_hi(v);
        }
    }
    unsigned int p = (unsigned int)f2bf(ax) | ((unsigned int)f2bf(ay) << 16);
    *reinterpret_cast<unsigned int*>(agg + (size_t)n * IN_F + lane2) = p;
}

// ---- GEMM1 (MFMA): h1[M,256] = agg[M,128] @ W1, bf16 out ----------------
__global__ __launch_bounds__(256) void gemm1_mfma(
    const unsigned short* __restrict__ agg, const unsigned short* __restrict__ w1s,
    unsigned short* __restrict__ h1, int nNodes)
{
    int wave = threadIdx.x >> 6, lane = threadIdx.x & 63;
    int m0 = blockIdx.x * 64 + wave * 16;
    if (m0 >= nNodes) return;
    int row = lane & 15, quad = lane >> 4;
    f32x4 acc[16] = {};
    const bf16x8* aBase = reinterpret_cast<const bf16x8*>(
        agg + (size_t)(m0 + row) * IN_F + quad * 8);
    const bf16x8* bBase = reinterpret_cast<const bf16x8*>(w1s) + lane;
    #pragma unroll
    for (int ks = 0; ks < 4; ++ks) {
        bf16x8 a = aBase[ks * 4];
        #pragma unroll
        for (int nt = 0; nt < 16; ++nt) {
            bf16x8 b = bBase[(nt * 4 + ks) * 64];
            acc[nt] = __builtin_amdgcn_mfma_f32_16x16x32_bf16(a, b, acc[nt], 0, 0, 0);
        }
    }
    size_t outBase = (size_t)(m0 + quad * 4) * HID_F + row;
    #pragma unroll
    for (int i = 0; i < 4; ++i) {
        if (m0 + quad * 4 + i >= nNodes) break;   // tail guard
        #pragma unroll
        for (int nt = 0; nt < 16; ++nt)
            h1[outBase + (size_t)i * HID_F + nt * 16] = f2bf(acc[nt][i]);
    }
}

// ---- GEMM2 (MFMA): z[M,64] = h1[M,256] @ W2, bf16 out -------------------
__global__ __launch_bounds__(256) void gemm2_mfma(
    const unsigned short* __restrict__ h1, const unsigned short* __restrict__ w2s,
    unsigned short* __restrict__ z, int nNodes)
{
    int wave = threadIdx.x >> 6, lane = threadIdx.x & 63;
    int m0 = blockIdx.x * 64 + wave * 16;
    if (m0 >= nNodes) return;
    int row = lane & 15, quad = lane >> 4;
    f32x4 acc[4] = {};
    const bf16x8* aBase = reinterpret_cast<const bf16x8*>(
        h1 + (size_t)(m0 + row) * HID_F + quad * 8);
    const bf16x8* bBase = reinterpret_cast<const bf16x8*>(w2s) + lane;
    #pragma unroll
    for (int ks = 0; ks < 8; ++ks) {
        bf16x8 a = aBase[ks * 4];
        #pragma unroll
        for (int nt = 0; nt < 4; ++nt) {
            bf16x8 b = bBase[(nt * 8 + ks) * 64];
            acc[nt] = __builtin_amdgcn_mfma_f32_16x16x32_bf16(a, b, acc[nt], 0, 0, 0);
        }
    }
    size_t outBase = (size_t)(m0 + quad * 4) * OUT_F + row;
    #pragma unroll
    for (int i = 0; i < 4; ++i) {
        if (m0 + quad * 4 + i >= nNodes) break;   // tail guard
        #pragma unroll
        for (int nt = 0; nt < 4; ++nt)
            z[outBase + (size_t)i * OUT_F + nt * 16] = f2bf(acc[nt][i]);
    }
}

// ---- Layer-2 gather (commuted): out[n] = z[n] + sum z[src] --------------
// Same scalarized addressing + 16-deep unroll as gather1.
__global__ __launch_bounds__(256) void gather2(
    const unsigned short* __restrict__ z, const int* __restrict__ rowptr,
    const int* __restrict__ eidx, float* __restrict__ out, int nNodes)
{
    int n    = blockIdx.x * 4 + __builtin_amdgcn_readfirstlane(threadIdx.x >> 6);
    int lane = threadIdx.x & 63;
    if (n >= nNodes) return;
    int beg = __builtin_amdgcn_readfirstlane(rowptr[n]);
    int end = __builtin_amdgcn_readfirstlane(rowptr[n + 1]);
    float acc = bf2f(z[(size_t)n * OUT_F + lane]);
    for (int base = beg; base < end; base += 64) {
        int cnt = min(64, end - base);
        int e = (base + lane < end) ? eidx[base + lane] : 0;
        int i = 0;
        for (; i + 16 <= cnt; i += 16) {
            unsigned short v[16];
            #pragma unroll
            for (int j = 0; j < 16; ++j) {
                int s = __builtin_amdgcn_readlane(e, i + j);
                v[j] = z[(size_t)s * OUT_F + lane];
            }
            #pragma unroll
            for (int j = 0; j < 16; ++j) acc += bf2f(v[j]);
        }
        for (; i + 4 <= cnt; i += 4) {
            int s0 = __builtin_amdgcn_readlane(e, i);
            int s1 = __builtin_amdgcn_readlane(e, i + 1);
            int s2 = __builtin_amdgcn_readlane(e, i + 2);
            int s3 = __builtin_amdgcn_readlane(e, i + 3);
            unsigned short v0 = z[(size_t)s0 * OUT_F + lane];
            unsigned short v1 = z[(size_t)s1 * OUT_F + lane];
            unsigned short v2 = z[(size_t)s2 * OUT_F + lane];
            unsigned short v3 = z[(size_t)s3 * OUT_F + lane];
            acc += bf2f(v0) + bf2f(v1) + bf2f(v2) + bf2f(v3);
        }
        for (; i < cnt; ++i) {
            int s = __builtin_amdgcn_readlane(e, i);
            acc += bf2f(z[(size_t)s * OUT_F + lane]);
        }
    }
    out[(size_t)n * OUT_F + lane] = acc;
}

extern "C" void kernel_launch(void* const* d_in, const int* in_sizes, int n_in,
                              void* d_out, int out_size, void* d_ws, size_t ws_size,
                              hipStream_t stream) {
    const float* x  = (const float*)d_in[0];
    const int* esrc = (const int*)d_in[1];
    const int* edst = (const int*)d_in[2];
    const float* W1 = (const float*)d_in[3];
    const float* W2 = (const float*)d_in[4];
    float* out      = (float*)d_out;

    const int nNodes = in_sizes[0] / IN_F;
    const int nEdges = in_sizes[1];
    const int NB = (nNodes + BUCKET_SZ - 1) / BUCKET_SZ;   // 196 (must be <= 256)
    const int A  = (nEdges + EPB - 1) / EPB;               // 196 binning blocks

    // Workspace (~96.7 MB; 110.4 MB known-safe from R3):
    char* ws = (char*)d_ws;
    const size_t h1_b     = (size_t)nNodes * HID_F * sizeof(unsigned short);
    const size_t aggz_b   = (size_t)nNodes * IN_F * sizeof(unsigned short);
    const size_t binned_b = (size_t)nEdges * sizeof(unsigned long long);
    const size_t eidx_b   = (size_t)nEdges * sizeof(int);
    unsigned short* h1  = (unsigned short*)ws;
    unsigned short* xb  = (unsigned short*)ws;                   // alias of h1
    unsigned short* agg = (unsigned short*)(ws + h1_b);
    unsigned short* z   = (unsigned short*)(ws + h1_b);          // alias of agg
    unsigned long long* binned = (unsigned long long*)(ws + h1_b + aggz_b);
    int* eidx           = (int*)(ws + h1_b + aggz_b + binned_b);
    unsigned short* w1s = (unsigned short*)(ws + h1_b + aggz_b + binned_b + eidx_b);
    unsigned short* w2s = w1s + IN_F * HID_F;
    int* rowptr     = (int*)(w2s + HID_F * OUT_F);
    int* counts     = rowptr + (nNodes + 1);
    int* bucketBase = counts + (size_t)NB * A;
    int* btot       = bucketBase + (NB + 1);

    k_wconv<<<(IN_F * HID_F + 255) / 256, 256, 0, stream>>>(W1, W2, w1s, w2s);

    long long total8 = (long long)nNodes * IN_F / 8;
    k_xconv<<<(int)((total8 + 255) / 256), 256, 0, stream>>>(x, xb, total8);

    k_hist<<<A, 256, 0, stream>>>(edst, counts, nEdges, NB);
    k_btot<<<NB, 256, 0, stream>>>(counts, btot, A);
    k_scanNB<<<1, 256, 0, stream>>>(btot, bucketBase, rowptr, NB, nNodes, nEdges);
    k_cursor<<<NB, 256, 0, stream>>>(counts, bucketBase, A);
    k_bin<<<A, 256, 0, stream>>>(esrc, edst, counts, binned, nEdges, NB);
    k_localcsr<<<NB, 256, 0, stream>>>(binned, bucketBase, rowptr, eidx, nNodes);

    const int nBlocks = (nNodes + 3) / 4;
    const int mBlocks = (nNodes + 63) / 64;
    gather1<<<nBlocks, 256, 0, stream>>>(xb, rowptr, eidx, agg, nNodes);
    gemm1_mfma<<<mBlocks, 256, 0, stream>>>(agg, w1s, h1, nNodes);
    gemm2_mfma<<<mBlocks, 256, 0, stream>>>(h1, w2s, z, nNodes);
    gather2<<<nBlocks, 256, 0, stream>>>(z, rowptr, eidx, out, nNodes);
}

// Round 3
// 316.732 us; speedup vs baseline: 1.0893x; 1.0511x over previous
//
#include <hip/hip_runtime.h>
#include <hip/hip_bf16.h>

#define IN_F  128
#define HID_F 256
#define OUT_F 64
#define BUCKET_SHIFT 9
#define BUCKET_SZ 512
#define EPB 8192            // edges per binning block

typedef __attribute__((ext_vector_type(8))) short bf16x8;
typedef __attribute__((ext_vector_type(4))) float f32x4;

__device__ __forceinline__ float bf2f(unsigned short u) {
    union { unsigned int i; float f; } v; v.i = ((unsigned int)u) << 16; return v.f;
}
__device__ __forceinline__ float bf2f_lo(unsigned int p) {
    union { unsigned int i; float f; } v; v.i = p << 16; return v.f;
}
__device__ __forceinline__ float bf2f_hi(unsigned int p) {
    union { unsigned int i; float f; } v; v.i = p & 0xffff0000u; return v.f;
}
__device__ __forceinline__ unsigned short f2bf(float f) {
    __hip_bfloat16 b = __float2bfloat16(f);
    return *reinterpret_cast<unsigned short*>(&b);
}

// ---- x fp32 -> bf16 (8 elems/thread) ------------------------------------
__global__ __launch_bounds__(256) void k_xconv(
    const float* __restrict__ x, unsigned short* __restrict__ xb, long long total8)
{
    long long i = (long long)blockIdx.x * blockDim.x + threadIdx.x;
    if (i >= total8) return;
    const float4* p = reinterpret_cast<const float4*>(x) + i * 2;
    float4 a = p[0], b = p[1];
    ushort4 o0, o1;
    o0.x = f2bf(a.x); o0.y = f2bf(a.y); o0.z = f2bf(a.z); o0.w = f2bf(a.w);
    o1.x = f2bf(b.x); o1.y = f2bf(b.y); o1.z = f2bf(b.z); o1.w = f2bf(b.w);
    reinterpret_cast<ushort4*>(xb)[i * 2]     = o0;
    reinterpret_cast<ushort4*>(xb)[i * 2 + 1] = o1;
}

// ---- CSR build via bucketed multisplit (no global per-edge atomics) -----
// Phase 1: per-block LDS histogram over buckets -> counts[b*A + i]
__global__ __launch_bounds__(256) void k_hist(
    const int* __restrict__ dst, int* __restrict__ counts,
    int nEdges, int NB)
{
    __shared__ int hist[256];
    int t = threadIdx.x;
    hist[t] = 0;
    __syncthreads();
    long long base = (long long)blockIdx.x * EPB;
    #pragma unroll
    for (int k = 0; k < EPB / 256; ++k) {
        long long e = base + k * 256 + t;
        if (e < nEdges) atomicAdd(&hist[dst[e] >> BUCKET_SHIFT], 1);
    }
    __syncthreads();
    if (t < NB) counts[t * gridDim.x + blockIdx.x] = hist[t];
}

// Phase 2a: bucket totals (NB blocks, parallel reduce over A counts each).
__global__ __launch_bounds__(256) void k_btot(
    const int* __restrict__ counts, int* __restrict__ btot, int A)
{
    __shared__ int sh[256];
    int b = blockIdx.x, t = threadIdx.x;
    int s = 0;
    for (int i = t; i < A; i += 256) s += counts[(size_t)b * A + i];
    sh[t] = s; __syncthreads();
    for (int d = 128; d > 0; d >>= 1) {
        if (t < d) sh[t] += sh[t + d];
        __syncthreads();
    }
    if (t == 0) btot[b] = sh[0];
}

// Phase 2b: one block scans NB totals -> bucketBase (exclusive).
__global__ __launch_bounds__(256) void k_scanNB(
    const int* __restrict__ btot, int* __restrict__ bucketBase,
    int* __restrict__ rowptr, int NB, int nNodes, int nEdges)
{
    __shared__ int sh[256];
    int t = threadIdx.x;
    int v = (t < NB) ? btot[t] : 0;
    sh[t] = v; __syncthreads();
    for (int d = 1; d < 256; d <<= 1) {
        int add = (t >= d) ? sh[t - d] : 0;
        __syncthreads();
        sh[t] += add;
        __syncthreads();
    }
    if (t < NB) bucketBase[t] = sh[t] - v;
    if (t == 0) { bucketBase[NB] = nEdges; rowptr[nNodes] = nEdges; }
}

// Phase 2c: per-bucket exclusive scan of its A counts + base -> start cursors.
__global__ __launch_bounds__(256) void k_cursor(
    int* __restrict__ counts, const int* __restrict__ bucketBase, int A)
{
    __shared__ int sh[256];
    int b = blockIdx.x, t = threadIdx.x;
    int run = bucketBase[b];
    for (int base = 0; base < A; base += 256) {
        int idx = base + t;
        int v = (idx < A) ? counts[(size_t)b * A + idx] : 0;
        sh[t] = v; __syncthreads();
        for (int d = 1; d < 256; d <<= 1) {
            int add = (t >= d) ? sh[t - d] : 0;
            __syncthreads();
            sh[t] += add;
            __syncthreads();
        }
        if (idx < A) counts[(size_t)b * A + idx] = run + sh[t] - v;
        run += sh[255];
        __syncthreads();
    }
}

// Phase 3: place (src,dst) pairs into bucket-contiguous binned[] (8B stores).
__global__ __launch_bounds__(256) void k_bin(
    const int* __restrict__ src, const int* __restrict__ dst,
    const int* __restrict__ counts, unsigned long long* __restrict__ binned,
    int nEdges, int NB)
{
    __shared__ int cur[256];
    int t = threadIdx.x;
    if (t < NB) cur[t] = counts[t * gridDim.x + blockIdx.x];
    __syncthreads();
    long long base = (long long)blockIdx.x * EPB;
    #pragma unroll
    for (int k = 0; k < EPB / 256; ++k) {
        long long e = base + k * 256 + t;
        if (e < nEdges) {
            int s = src[e], d = dst[e];
            int pos = atomicAdd(&cur[d >> BUCKET_SHIFT], 1);
            binned[pos] = (((unsigned long long)(unsigned)d) << 32) | (unsigned)s;
        }
    }
}

// Phase 4: per-bucket local CSR: LDS deg hist -> LDS scan -> rowptr + eidx.
__global__ __launch_bounds__(256) void k_localcsr(
    const unsigned long long* __restrict__ binned, const int* __restrict__ bucketBase,
    int* __restrict__ rowptr, int* __restrict__ eidx, int nNodes)
{
    __shared__ int ldeg[BUCKET_SZ];
    __shared__ int lscan[256];
    int t = threadIdx.x;
    ldeg[t] = 0; ldeg[t + 256] = 0;
    __syncthreads();
    int eb0 = bucketBase[blockIdx.x], eb1 = bucketBase[blockIdx.x + 1];
    int node0 = blockIdx.x << BUCKET_SHIFT;
    for (int e = eb0 + t; e < eb1; e += 256) {
        int d = (int)(binned[e] >> 32);
        atomicAdd(&ldeg[d - node0], 1);
    }
    __syncthreads();
    int d0 = ldeg[2 * t], d1 = ldeg[2 * t + 1];
    int s = d0 + d1;
    lscan[t] = s;
    __syncthreads();
    for (int d = 1; d < 256; d <<= 1) {
        int add = (t >= d) ? lscan[t - d] : 0;
        __syncthreads();
        lscan[t] += add;
        __syncthreads();
    }
    int excl = lscan[t] - s;
    ldeg[2 * t]     = excl;        // becomes local cursor
    ldeg[2 * t + 1] = excl + d0;
    int n0 = node0 + 2 * t;
    if (n0 < nNodes)     rowptr[n0]     = eb0 + excl;
    if (n0 + 1 < nNodes) rowptr[n0 + 1] = eb0 + excl + d0;
    __syncthreads();
    for (int e = eb0 + t; e < eb1; e += 256) {
        unsigned long long p = binned[e];
        int d = (int)(p >> 32), sv = (int)(p & 0xffffffffu);
        int pos = atomicAdd(&ldeg[d - node0], 1);
        eidx[eb0 + pos] = sv;
    }
}

// ---- Weight swizzle: fp32 W -> bf16 in B-fragment order -----------------
__global__ __launch_bounds__(256) void k_wconv(
    const float* __restrict__ W1, const float* __restrict__ W2,
    unsigned short* __restrict__ w1s, unsigned short* __restrict__ w2s)
{
    int idx = blockIdx.x * blockDim.x + threadIdx.x;
    if (idx < IN_F * HID_F) {            // W1: 16 ntiles x 4 ksteps
        int c = idx >> 9, L = (idx >> 3) & 63, j = idx & 7;
        int ntile = c >> 2, kstep = c & 3;
        int k = kstep * 32 + (L >> 4) * 8 + j;
        int n = ntile * 16 + (L & 15);
        w1s[idx] = f2bf(W1[k * HID_F + n]);
    }
    if (idx < HID_F * OUT_F) {           // W2: 4 ntiles x 8 ksteps
        int c = idx >> 9, L = (idx >> 3) & 63, j = idx & 7;
        int ntile = c >> 3, kstep = c & 7;
        int k = kstep * 32 + (L >> 4) * 8 + j;
        int n = ntile * 16 + (L & 15);
        w2s[idx] = f2bf(W2[k * OUT_F + n]);
    }
}

// ---- Layer-1 gather: agg[n] = xb[n] + sum xb[src] -----------------------
// Scalarized addressing (saddr loads) + 16-deep edge unroll.
__global__ __launch_bounds__(256) void gather1(
    const unsigned short* __restrict__ xb, const int* __restrict__ rowptr,
    const int* __restrict__ eidx, unsigned short* __restrict__ agg, int nNodes)
{
    int n    = blockIdx.x * 4 + __builtin_amdgcn_readfirstlane(threadIdx.x >> 6);
    int lane = threadIdx.x & 63;
    if (n >= nNodes) return;
    int beg = __builtin_amdgcn_readfirstlane(rowptr[n]);
    int end = __builtin_amdgcn_readfirstlane(rowptr[n + 1]);
    const size_t lane2 = (size_t)(lane * 2);
    unsigned int self = *reinterpret_cast<const unsigned int*>(
        xb + (size_t)n * IN_F + lane2);
    float ax = bf2f_lo(self), ay = bf2f_hi(self);
    for (int base = beg; base < end; base += 64) {
        int cnt = min(64, end - base);
        int e = (base + lane < end) ? eidx[base + lane] : 0;
        int i = 0;
        for (; i + 16 <= cnt; i += 16) {
            unsigned int v[16];
            #pragma unroll
            for (int j = 0; j < 16; ++j) {
                int s = __builtin_amdgcn_readlane(e, i + j);
                v[j] = *reinterpret_cast<const unsigned int*>(
                    xb + (size_t)s * IN_F + lane2);
            }
            #pragma unroll
            for (int j = 0; j < 16; ++j) {
                ax += bf2f_lo(v[j]); ay += bf2f_hi(v[j]);
            }
        }
        for (; i + 4 <= cnt; i += 4) {
            int s0 = __builtin_amdgcn_readlane(e, i);
            int s1 = __builtin_amdgcn_readlane(e, i + 1);
            int s2 = __builtin_amdgcn_readlane(e, i + 2);
            int s3 = __builtin_amdgcn_readlane(e, i + 3);
            unsigned int v0 = *reinterpret_cast<const unsigned int*>(xb + (size_t)s0 * IN_F + lane2);
            unsigned int v1 = *reinterpret_cast<const unsigned int*>(xb + (size_t)s1 * IN_F + lane2);
            unsigned int v2 = *reinterpret_cast<const unsigned int*>(xb + (size_t)s2 * IN_F + lane2);
            unsigned int v3 = *reinterpret_cast<const unsigned int*>(xb + (size_t)s3 * IN_F + lane2);
            ax += bf2f_lo(v0) + bf2f_lo(v1) + bf2f_lo(v2) + bf2f_lo(v3);
            ay += bf2f_hi(v0) + bf2f_hi(v1) + bf2f_hi(v2) + bf2f_hi(v3);
        }
        for (; i < cnt; ++i) {
            int s = __builtin_amdgcn_readlane(e, i);
            unsigned int v = *reinterpret_cast<const unsigned int*>(xb + (size_t)s * IN_F + lane2);
            ax += bf2f_lo(v); ay += bf2f_hi(v);
        }
    }
    unsigned int p = (unsigned int)f2bf(ax) | ((unsigned int)f2bf(ay) << 16);
    *reinterpret_cast<unsigned int*>(agg + (size_t)n * IN_F + lane2) = p;
}

// ---- Fused MLP (MFMA): z[M,64] = (agg[M,128] @ W1) @ W2, bf16 out -------
// Each wave computes its 16x256 h1 tile, spills it to a wave-private
// XOR-swizzled LDS tile (no barrier: producer == consumer wave), reads
// back A-fragments, and runs gemm2. h1 never exists in global memory.
__global__ __launch_bounds__(256) void mlp_fused(
    const unsigned short* __restrict__ agg,
    const unsigned short* __restrict__ w1s,
    const unsigned short* __restrict__ w2s,
    unsigned short* __restrict__ z, int nNodes)
{
    __shared__ unsigned short h1t[4 * 16 * HID_F];   // 4 waves x 8 KB
    int wave = threadIdx.x >> 6, lane = threadIdx.x & 63;
    int m0 = blockIdx.x * 64 + wave * 16;
    if (m0 >= nNodes) return;
    int row = lane & 15, quad = lane >> 4;
    unsigned short* myt = h1t + wave * 16 * HID_F;

    // ---- gemm1: acc1 = agg_tile @ W1 ----
    f32x4 acc1[16] = {};
    const bf16x8* aBase = reinterpret_cast<const bf16x8*>(
        agg + (size_t)(m0 + row) * IN_F + quad * 8);
    const bf16x8* b1Base = reinterpret_cast<const bf16x8*>(w1s) + lane;
    #pragma unroll
    for (int ks = 0; ks < 4; ++ks) {
        bf16x8 a = aBase[ks * 4];
        #pragma unroll
        for (int nt = 0; nt < 16; ++nt) {
            bf16x8 b = b1Base[(nt * 4 + ks) * 64];
            acc1[nt] = __builtin_amdgcn_mfma_f32_16x16x32_bf16(a, b, acc1[nt], 0, 0, 0);
        }
    }

    // ---- spill h1 tile to LDS (bf16, XOR-swizzled rows) ----
    // element [r][c] at byte (r*512 + c*2) ^ ((r&7)<<4)
    #pragma unroll
    for (int i = 0; i < 4; ++i) {
        int r = quad * 4 + i;
        #pragma unroll
        for (int nt = 0; nt < 16; ++nt) {
            int c = nt * 16 + row;
            int b = ((r << 9) + (c << 1)) ^ ((r & 7) << 4);
            myt[b >> 1] = f2bf(acc1[nt][i]);
        }
    }
    // same-wave RAW on LDS: compiler inserts lgkmcnt wait; no barrier needed

    // ---- gemm2: acc2 = h1_tile @ W2 ----
    f32x4 acc2[4] = {};
    const bf16x8* b2Base = reinterpret_cast<const bf16x8*>(w2s) + lane;
    #pragma unroll
    for (int ks = 0; ks < 8; ++ks) {
        int b = ((row << 9) + ((quad * 8 + ks * 32) << 1)) ^ ((row & 7) << 4);
        bf16x8 a = *reinterpret_cast<const bf16x8*>(&myt[b >> 1]);
        #pragma unroll
        for (int nt = 0; nt < 4; ++nt) {
            bf16x8 bb = b2Base[(nt * 8 + ks) * 64];
            acc2[nt] = __builtin_amdgcn_mfma_f32_16x16x32_bf16(a, bb, acc2[nt], 0, 0, 0);
        }
    }
    size_t outBase = (size_t)(m0 + quad * 4) * OUT_F + row;
    #pragma unroll
    for (int i = 0; i < 4; ++i) {
        if (m0 + quad * 4 + i >= nNodes) break;   // tail guard
        #pragma unroll
        for (int nt = 0; nt < 4; ++nt)
            z[outBase + (size_t)i * OUT_F + nt * 16] = f2bf(acc2[nt][i]);
    }
}

// ---- Layer-2 gather (commuted): out[n] = z[n] + sum z[src] --------------
// Same scalarized addressing + 16-deep unroll as gather1.
__global__ __launch_bounds__(256) void gather2(
    const unsigned short* __restrict__ z, const int* __restrict__ rowptr,
    const int* __restrict__ eidx, float* __restrict__ out, int nNodes)
{
    int n    = blockIdx.x * 4 + __builtin_amdgcn_readfirstlane(threadIdx.x >> 6);
    int lane = threadIdx.x & 63;
    if (n >= nNodes) return;
    int beg = __builtin_amdgcn_readfirstlane(rowptr[n]);
    int end = __builtin_amdgcn_readfirstlane(rowptr[n + 1]);
    float acc = bf2f(z[(size_t)n * OUT_F + lane]);
    for (int base = beg; base < end; base += 64) {
        int cnt = min(64, end - base);
        int e = (base + lane < end) ? eidx[base + lane] : 0;
        int i = 0;
        for (; i + 16 <= cnt; i += 16) {
            unsigned short v[16];
            #pragma unroll
            for (int j = 0; j < 16; ++j) {
                int s = __builtin_amdgcn_readlane(e, i + j);
                v[j] = z[(size_t)s * OUT_F + lane];
            }
            #pragma unroll
            for (int j = 0; j < 16; ++j) acc += bf2f(v[j]);
        }
        for (; i + 4 <= cnt; i += 4) {
            int s0 = __builtin_amdgcn_readlane(e, i);
            int s1 = __builtin_amdgcn_readlane(e, i + 1);
            int s2 = __builtin_amdgcn_readlane(e, i + 2);
            int s3 = __builtin_amdgcn_readlane(e, i + 3);
            unsigned short v0 = z[(size_t)s0 * OUT_F + lane];
            unsigned short v1 = z[(size_t)s1 * OUT_F + lane];
            unsigned short v2 = z[(size_t)s2 * OUT_F + lane];
            unsigned short v3 = z[(size_t)s3 * OUT_F + lane];
            acc += bf2f(v0) + bf2f(v1) + bf2f(v2) + bf2f(v3);
        }
        for (; i < cnt; ++i) {
            int s = __builtin_amdgcn_readlane(e, i);
            acc += bf2f(z[(size_t)s * OUT_F + lane]);
        }
    }
    out[(size_t)n * OUT_F + lane] = acc;
}

extern "C" void kernel_launch(void* const* d_in, const int* in_sizes, int n_in,
                              void* d_out, int out_size, void* d_ws, size_t ws_size,
                              hipStream_t stream) {
    const float* x  = (const float*)d_in[0];
    const int* esrc = (const int*)d_in[1];
    const int* edst = (const int*)d_in[2];
    const float* W1 = (const float*)d_in[3];
    const float* W2 = (const float*)d_in[4];
    float* out      = (float*)d_out;

    const int nNodes = in_sizes[0] / IN_F;
    const int nEdges = in_sizes[1];
    const int NB = (nNodes + BUCKET_SZ - 1) / BUCKET_SZ;   // 196 (must be <= 256)
    const int A  = (nEdges + EPB - 1) / EPB;               // 196 binning blocks

    // Workspace (~84 MB; 110.4 MB known-safe). No aliasing: mlp_fused
    // reads agg and writes z concurrently across blocks.
    char* ws = (char*)d_ws;
    const size_t xb_b     = (size_t)nNodes * IN_F * sizeof(unsigned short);   // 25.6 MB
    const size_t agg_b    = (size_t)nNodes * IN_F * sizeof(unsigned short);   // 25.6 MB
    const size_t z_b      = (size_t)nNodes * OUT_F * sizeof(unsigned short);  // 12.8 MB
    const size_t binned_b = (size_t)nEdges * sizeof(unsigned long long);      // 12.8 MB
    const size_t eidx_b   = (size_t)nEdges * sizeof(int);                     //  6.4 MB
    unsigned short* xb  = (unsigned short*)ws;
    unsigned short* agg = (unsigned short*)(ws + xb_b);
    unsigned short* z   = (unsigned short*)(ws + xb_b + agg_b);
    unsigned long long* binned = (unsigned long long*)(ws + xb_b + agg_b + z_b);
    int* eidx           = (int*)(ws + xb_b + agg_b + z_b + binned_b);
    unsigned short* w1s = (unsigned short*)(ws + xb_b + agg_b + z_b + binned_b + eidx_b);
    unsigned short* w2s = w1s + IN_F * HID_F;
    int* rowptr     = (int*)(w2s + HID_F * OUT_F);
    int* counts     = rowptr + (nNodes + 1);
    int* bucketBase = counts + (size_t)NB * A;
    int* btot       = bucketBase + (NB + 1);

    k_wconv<<<(IN_F * HID_F + 255) / 256, 256, 0, stream>>>(W1, W2, w1s, w2s);

    long long total8 = (long long)nNodes * IN_F / 8;
    k_xconv<<<(int)((total8 + 255) / 256), 256, 0, stream>>>(x, xb, total8);

    k_hist<<<A, 256, 0, stream>>>(edst, counts, nEdges, NB);
    k_btot<<<NB, 256, 0, stream>>>(counts, btot, A);
    k_scanNB<<<1, 256, 0, stream>>>(btot, bucketBase, rowptr, NB, nNodes, nEdges);
    k_cursor<<<NB, 256, 0, stream>>>(counts, bucketBase, A);
    k_bin<<<A, 256, 0, stream>>>(esrc, edst, counts, binned, nEdges, NB);
    k_localcsr<<<NB, 256, 0, stream>>>(binned, bucketBase, rowptr, eidx, nNodes);

    const int nBlocks = (nNodes + 3) / 4;
    const int mBlocks = (nNodes + 63) / 64;
    gather1<<<nBlocks, 256, 0, stream>>>(xb, rowptr, eidx, agg, nNodes);
    mlp_fused<<<mBlocks, 256, 0, stream>>>(agg, w1s, w2s, z, nNodes);
    gather2<<<nBlocks, 256, 0, stream>>>(z, rowptr, eidx, out, nNodes);
}

// Round 4
// 310.309 us; speedup vs baseline: 1.1118x; 1.0207x over previous
//
#include <hip/hip_runtime.h>
#include <hip/hip_bf16.h>

#define IN_F  128
#define HID_F 256
#define OUT_F 64
#define BUCKET_SHIFT 9
#define BUCKET_SZ 512
#define EPB 8192            // edges per binning block

typedef __attribute__((ext_vector_type(8))) short bf16x8;
typedef __attribute__((ext_vector_type(4))) float f32x4;

__device__ __forceinline__ float bf2f(unsigned short u) {
    union { unsigned int i; float f; } v; v.i = ((unsigned int)u) << 16; return v.f;
}
__device__ __forceinline__ float bf2f_lo(unsigned int p) {
    union { unsigned int i; float f; } v; v.i = p << 16; return v.f;
}
__device__ __forceinline__ float bf2f_hi(unsigned int p) {
    union { unsigned int i; float f; } v; v.i = p & 0xffff0000u; return v.f;
}
__device__ __forceinline__ unsigned short f2bf(float f) {
    __hip_bfloat16 b = __float2bfloat16(f);
    return *reinterpret_cast<unsigned short*>(&b);
}

// ---- x fp32 -> bf16 (8 elems/thread) ------------------------------------
__global__ __launch_bounds__(256) void k_xconv(
    const float* __restrict__ x, unsigned short* __restrict__ xb, long long total8)
{
    long long i = (long long)blockIdx.x * blockDim.x + threadIdx.x;
    if (i >= total8) return;
    const float4* p = reinterpret_cast<const float4*>(x) + i * 2;
    float4 a = p[0], b = p[1];
    ushort4 o0, o1;
    o0.x = f2bf(a.x); o0.y = f2bf(a.y); o0.z = f2bf(a.z); o0.w = f2bf(a.w);
    o1.x = f2bf(b.x); o1.y = f2bf(b.y); o1.z = f2bf(b.z); o1.w = f2bf(b.w);
    reinterpret_cast<ushort4*>(xb)[i * 2]     = o0;
    reinterpret_cast<ushort4*>(xb)[i * 2 + 1] = o1;
}

// ---- CSR build via bucketed multisplit (no global per-edge atomics) -----
// Phase 1: per-block LDS histogram over buckets -> counts[b*A + i]
__global__ __launch_bounds__(256) void k_hist(
    const int* __restrict__ dst, int* __restrict__ counts,
    int nEdges, int NB)
{
    __shared__ int hist[256];
    int t = threadIdx.x;
    hist[t] = 0;
    __syncthreads();
    long long base = (long long)blockIdx.x * EPB;
    #pragma unroll
    for (int k = 0; k < EPB / 256; ++k) {
        long long e = base + k * 256 + t;
        if (e < nEdges) atomicAdd(&hist[dst[e] >> BUCKET_SHIFT], 1);
    }
    __syncthreads();
    if (t < NB) counts[t * gridDim.x + blockIdx.x] = hist[t];
}

// Phase 2a: bucket totals (NB blocks, parallel reduce over A counts each).
__global__ __launch_bounds__(256) void k_btot(
    const int* __restrict__ counts, int* __restrict__ btot, int A)
{
    __shared__ int sh[256];
    int b = blockIdx.x, t = threadIdx.x;
    int s = 0;
    for (int i = t; i < A; i += 256) s += counts[(size_t)b * A + i];
    sh[t] = s; __syncthreads();
    for (int d = 128; d > 0; d >>= 1) {
        if (t < d) sh[t] += sh[t + d];
        __syncthreads();
    }
    if (t == 0) btot[b] = sh[0];
}

// Phase 2b: one block scans NB totals -> bucketBase (exclusive).
__global__ __launch_bounds__(256) void k_scanNB(
    const int* __restrict__ btot, int* __restrict__ bucketBase,
    int* __restrict__ rowptr, int NB, int nNodes, int nEdges)
{
    __shared__ int sh[256];
    int t = threadIdx.x;
    int v = (t < NB) ? btot[t] : 0;
    sh[t] = v; __syncthreads();
    for (int d = 1; d < 256; d <<= 1) {
        int add = (t >= d) ? sh[t - d] : 0;
        __syncthreads();
        sh[t] += add;
        __syncthreads();
    }
    if (t < NB) bucketBase[t] = sh[t] - v;
    if (t == 0) { bucketBase[NB] = nEdges; rowptr[nNodes] = nEdges; }
}

// Phase 2c: per-bucket exclusive scan of its A counts + base -> start cursors.
__global__ __launch_bounds__(256) void k_cursor(
    int* __restrict__ counts, const int* __restrict__ bucketBase, int A)
{
    __shared__ int sh[256];
    int b = blockIdx.x, t = threadIdx.x;
    int run = bucketBase[b];
    for (int base = 0; base < A; base += 256) {
        int idx = base + t;
        int v = (idx < A) ? counts[(size_t)b * A + idx] : 0;
        sh[t] = v; __syncthreads();
        for (int d = 1; d < 256; d <<= 1) {
            int add = (t >= d) ? sh[t - d] : 0;
            __syncthreads();
            sh[t] += add;
            __syncthreads();
        }
        if (idx < A) counts[(size_t)b * A + idx] = run + sh[t] - v;
        run += sh[255];
        __syncthreads();
    }
}

// Phase 3: place (src,dst) pairs into bucket-contiguous binned[] (8B stores).
__global__ __launch_bounds__(256) void k_bin(
    const int* __restrict__ src, const int* __restrict__ dst,
    const int* __restrict__ counts, unsigned long long* __restrict__ binned,
    int nEdges, int NB)
{
    __shared__ int cur[256];
    int t = threadIdx.x;
    if (t < NB) cur[t] = counts[t * gridDim.x + blockIdx.x];
    __syncthreads();
    long long base = (long long)blockIdx.x * EPB;
    #pragma unroll
    for (int k = 0; k < EPB / 256; ++k) {
        long long e = base + k * 256 + t;
        if (e < nEdges) {
            int s = src[e], d = dst[e];
            int pos = atomicAdd(&cur[d >> BUCKET_SHIFT], 1);
            binned[pos] = (((unsigned long long)(unsigned)d) << 32) | (unsigned)s;
        }
    }
}

// Phase 4: per-bucket local CSR: LDS deg hist -> LDS scan -> rowptr + eidx.
__global__ __launch_bounds__(256) void k_localcsr(
    const unsigned long long* __restrict__ binned, const int* __restrict__ bucketBase,
    int* __restrict__ rowptr, int* __restrict__ eidx, int nNodes)
{
    __shared__ int ldeg[BUCKET_SZ];
    __shared__ int lscan[256];
    int t = threadIdx.x;
    ldeg[t] = 0; ldeg[t + 256] = 0;
    __syncthreads();
    int eb0 = bucketBase[blockIdx.x], eb1 = bucketBase[blockIdx.x + 1];
    int node0 = blockIdx.x << BUCKET_SHIFT;
    for (int e = eb0 + t; e < eb1; e += 256) {
        int d = (int)(binned[e] >> 32);
        atomicAdd(&ldeg[d - node0], 1);
    }
    __syncthreads();
    int d0 = ldeg[2 * t], d1 = ldeg[2 * t + 1];
    int s = d0 + d1;
    lscan[t] = s;
    __syncthreads();
    for (int d = 1; d < 256; d <<= 1) {
        int add = (t >= d) ? lscan[t - d] : 0;
        __syncthreads();
        lscan[t] += add;
        __syncthreads();
    }
    int excl = lscan[t] - s;
    ldeg[2 * t]     = excl;        // becomes local cursor
    ldeg[2 * t + 1] = excl + d0;
    int n0 = node0 + 2 * t;
    if (n0 < nNodes)     rowptr[n0]     = eb0 + excl;
    if (n0 + 1 < nNodes) rowptr[n0 + 1] = eb0 + excl + d0;
    __syncthreads();
    for (int e = eb0 + t; e < eb1; e += 256) {
        unsigned long long p = binned[e];
        int d = (int)(p >> 32), sv = (int)(p & 0xffffffffu);
        int pos = atomicAdd(&ldeg[d - node0], 1);
        eidx[eb0 + pos] = sv;
    }
}

// ---- Weight swizzle: fp32 W -> bf16 in B-fragment order -----------------
__global__ __launch_bounds__(256) void k_wconv(
    const float* __restrict__ W1, const float* __restrict__ W2,
    unsigned short* __restrict__ w1s, unsigned short* __restrict__ w2s)
{
    int idx = blockIdx.x * blockDim.x + threadIdx.x;
    if (idx < IN_F * HID_F) {            // W1: 16 ntiles x 4 ksteps
        int c = idx >> 9, L = (idx >> 3) & 63, j = idx & 7;
        int ntile = c >> 2, kstep = c & 3;
        int k = kstep * 32 + (L >> 4) * 8 + j;
        int n = ntile * 16 + (L & 15);
        w1s[idx] = f2bf(W1[k * HID_F + n]);
    }
    if (idx < HID_F * OUT_F) {           // W2: 4 ntiles x 8 ksteps
        int c = idx >> 9, L = (idx >> 3) & 63, j = idx & 7;
        int ntile = c >> 3, kstep = c & 7;
        int k = kstep * 32 + (L >> 4) * 8 + j;
        int n = ntile * 16 + (L & 15);
        w2s[idx] = f2bf(W2[k * OUT_F + n]);
    }
}

// ---- Layer-1 gather: agg[n] = xb[n] + sum xb[src] -----------------------
// Wide-gather: one wave = one node; 16 lanes cover a 256B row (dwordx4 per
// lane), so one instruction gathers 4 edges' rows. 4x fewer vmem
// instructions / TA addresses than the 4B-per-lane form; same bytes/lines.
__global__ __launch_bounds__(256) void gather1(
    const unsigned short* __restrict__ xb, const int* __restrict__ rowptr,
    const int* __restrict__ eidx, unsigned short* __restrict__ agg, int nNodes)
{
    int n    = blockIdx.x * 4 + __builtin_amdgcn_readfirstlane(threadIdx.x >> 6);
    int lane = threadIdx.x & 63;
    if (n >= nNodes) return;
    int beg = __builtin_amdgcn_readfirstlane(rowptr[n]);
    int end = __builtin_amdgcn_readfirstlane(rowptr[n + 1]);
    int g = lane >> 4;          // edge subgroup 0..3
    int f = lane & 15;          // 16B chunk within row
    float acc[8] = {0.f, 0.f, 0.f, 0.f, 0.f, 0.f, 0.f, 0.f};

    for (int e0 = beg; e0 < end; e0 += 64) {
        int cnt = min(64, end - e0);                 // uniform
        int e = (lane < cnt) ? eidx[e0 + lane] : 0;
        for (int i = 0; i < cnt; i += 16) {          // 16 edges per block
            uint4 v[4];
            unsigned int vmask[4];
            #pragma unroll
            for (int j = 0; j < 4; ++j) {
                int eij = i + 4 * j + g;
                int src = __builtin_amdgcn_ds_bpermute(eij << 2, e);
                int s0  = __builtin_amdgcn_readlane(e, i + 4 * j);
                bool valid = eij < cnt;
                vmask[j] = valid ? 0xffffffffu : 0u;
                src = valid ? src : s0;              // same lines, no extra fetch
                v[j] = *reinterpret_cast<const uint4*>(
                    xb + (unsigned)src * IN_F + (f << 3));
            }
            #pragma unroll
            for (int j = 0; j < 4; ++j) {
                unsigned int a0 = v[j].x & vmask[j], a1 = v[j].y & vmask[j];
                unsigned int a2 = v[j].z & vmask[j], a3 = v[j].w & vmask[j];
                acc[0] += bf2f_lo(a0); acc[1] += bf2f_hi(a0);
                acc[2] += bf2f_lo(a1); acc[3] += bf2f_hi(a1);
                acc[4] += bf2f_lo(a2); acc[5] += bf2f_hi(a2);
                acc[6] += bf2f_lo(a3); acc[7] += bf2f_hi(a3);
            }
        }
    }
    // cross-subgroup reduce (lanes f, f+16, f+32, f+48 hold same features)
    #pragma unroll
    for (int k = 0; k < 8; ++k) {
        acc[k] += __shfl_xor(acc[k], 16);
        acc[k] += __shfl_xor(acc[k], 32);
    }
    // self row add (all lanes redundantly; values identical across groups)
    uint4 sv = *reinterpret_cast<const uint4*>(xb + (size_t)n * IN_F + (f << 3));
    acc[0] += bf2f_lo(sv.x); acc[1] += bf2f_hi(sv.x);
    acc[2] += bf2f_lo(sv.y); acc[3] += bf2f_hi(sv.y);
    acc[4] += bf2f_lo(sv.z); acc[5] += bf2f_hi(sv.z);
    acc[6] += bf2f_lo(sv.w); acc[7] += bf2f_hi(sv.w);
    if (g == 0) {
        uint4 o;
        o.x = (unsigned int)f2bf(acc[0]) | ((unsigned int)f2bf(acc[1]) << 16);
        o.y = (unsigned int)f2bf(acc[2]) | ((unsigned int)f2bf(acc[3]) << 16);
        o.z = (unsigned int)f2bf(acc[4]) | ((unsigned int)f2bf(acc[5]) << 16);
        o.w = (unsigned int)f2bf(acc[6]) | ((unsigned int)f2bf(acc[7]) << 16);
        *reinterpret_cast<uint4*>(agg + (size_t)n * IN_F + (f << 3)) = o;
    }
}

// ---- Fused MLP (MFMA): z[M,64] = (agg[M,128] @ W1) @ W2, bf16 out -------
__global__ __launch_bounds__(256) void mlp_fused(
    const unsigned short* __restrict__ agg,
    const unsigned short* __restrict__ w1s,
    const unsigned short* __restrict__ w2s,
    unsigned short* __restrict__ z, int nNodes)
{
    __shared__ unsigned short h1t[4 * 16 * HID_F];   // 4 waves x 8 KB
    int wave = threadIdx.x >> 6, lane = threadIdx.x & 63;
    int m0 = blockIdx.x * 64 + wave * 16;
    if (m0 >= nNodes) return;
    int row = lane & 15, quad = lane >> 4;
    unsigned short* myt = h1t + wave * 16 * HID_F;

    // ---- gemm1: acc1 = agg_tile @ W1 ----
    f32x4 acc1[16] = {};
    const bf16x8* aBase = reinterpret_cast<const bf16x8*>(
        agg + (size_t)(m0 + row) * IN_F + quad * 8);
    const bf16x8* b1Base = reinterpret_cast<const bf16x8*>(w1s) + lane;
    #pragma unroll
    for (int ks = 0; ks < 4; ++ks) {
        bf16x8 a = aBase[ks * 4];
        #pragma unroll
        for (int nt = 0; nt < 16; ++nt) {
            bf16x8 b = b1Base[(nt * 4 + ks) * 64];
            acc1[nt] = __builtin_amdgcn_mfma_f32_16x16x32_bf16(a, b, acc1[nt], 0, 0, 0);
        }
    }

    // ---- spill h1 tile to LDS (bf16, XOR-swizzled rows) ----
    #pragma unroll
    for (int i = 0; i < 4; ++i) {
        int r = quad * 4 + i;
        #pragma unroll
        for (int nt = 0; nt < 16; ++nt) {
            int c = nt * 16 + row;
            int b = ((r << 9) + (c << 1)) ^ ((r & 7) << 4);
            myt[b >> 1] = f2bf(acc1[nt][i]);
        }
    }
    // same-wave RAW on LDS: compiler inserts lgkmcnt wait; no barrier needed

    // ---- gemm2: acc2 = h1_tile @ W2 ----
    f32x4 acc2[4] = {};
    const bf16x8* b2Base = reinterpret_cast<const bf16x8*>(w2s) + lane;
    #pragma unroll
    for (int ks = 0; ks < 8; ++ks) {
        int b = ((row << 9) + ((quad * 8 + ks * 32) << 1)) ^ ((row & 7) << 4);
        bf16x8 a = *reinterpret_cast<const bf16x8*>(&myt[b >> 1]);
        #pragma unroll
        for (int nt = 0; nt < 4; ++nt) {
            bf16x8 bb = b2Base[(nt * 8 + ks) * 64];
            acc2[nt] = __builtin_amdgcn_mfma_f32_16x16x32_bf16(a, bb, acc2[nt], 0, 0, 0);
        }
    }
    size_t outBase = (size_t)(m0 + quad * 4) * OUT_F + row;
    #pragma unroll
    for (int i = 0; i < 4; ++i) {
        if (m0 + quad * 4 + i >= nNodes) break;   // tail guard
        #pragma unroll
        for (int nt = 0; nt < 4; ++nt)
            z[outBase + (size_t)i * OUT_F + nt * 16] = f2bf(acc2[nt][i]);
    }
}

// ---- Layer-2 gather (commuted): out[n] = z[n] + sum z[src] --------------
// Wide-gather: 8 lanes cover a 128B z-row (dwordx4/lane) -> 8 edges/instr.
__global__ __launch_bounds__(256) void gather2(
    const unsigned short* __restrict__ z, const int* __restrict__ rowptr,
    const int* __restrict__ eidx, float* __restrict__ out, int nNodes)
{
    int n    = blockIdx.x * 4 + __builtin_amdgcn_readfirstlane(threadIdx.x >> 6);
    int lane = threadIdx.x & 63;
    if (n >= nNodes) return;
    int beg = __builtin_amdgcn_readfirstlane(rowptr[n]);
    int end = __builtin_amdgcn_readfirstlane(rowptr[n + 1]);
    int g = lane >> 3;          // edge subgroup 0..7
    int f = lane & 7;           // 16B chunk within row
    float acc[8] = {0.f, 0.f, 0.f, 0.f, 0.f, 0.f, 0.f, 0.f};

    for (int e0 = beg; e0 < end; e0 += 64) {
        int cnt = min(64, end - e0);                 // uniform
        int e = (lane < cnt) ? eidx[e0 + lane] : 0;
        for (int i = 0; i < cnt; i += 32) {          // 32 edges per block
            uint4 v[4];
            unsigned int vmask[4];
            #pragma unroll
            for (int j = 0; j < 4; ++j) {
                int eij = i + 8 * j + g;
                int src = __builtin_amdgcn_ds_bpermute(eij << 2, e);
                int s0  = __builtin_amdgcn_readlane(e, i + 8 * j);
                bool valid = eij < cnt;
                vmask[j] = valid ? 0xffffffffu : 0u;
                src = valid ? src : s0;
                v[j] = *reinterpret_cast<const uint4*>(
                    z + (unsigned)src * OUT_F + (f << 3));
            }
            #pragma unroll
            for (int j = 0; j < 4; ++j) {
                unsigned int a0 = v[j].x & vmask[j], a1 = v[j].y & vmask[j];
                unsigned int a2 = v[j].z & vmask[j], a3 = v[j].w & vmask[j];
                acc[0] += bf2f_lo(a0); acc[1] += bf2f_hi(a0);
                acc[2] += bf2f_lo(a1); acc[3] += bf2f_hi(a1);
                acc[4] += bf2f_lo(a2); acc[5] += bf2f_hi(a2);
                acc[6] += bf2f_lo(a3); acc[7] += bf2f_hi(a3);
            }
        }
    }
    // cross-subgroup reduce (8 groups share feature chunks)
    #pragma unroll
    for (int k = 0; k < 8; ++k) {
        acc[k] += __shfl_xor(acc[k], 8);
        acc[k] += __shfl_xor(acc[k], 16);
        acc[k] += __shfl_xor(acc[k], 32);
    }
    // self row add
    uint4 sv = *reinterpret_cast<const uint4*>(z + (size_t)n * OUT_F + (f << 3));
    acc[0] += bf2f_lo(sv.x); acc[1] += bf2f_hi(sv.x);
    acc[2] += bf2f_lo(sv.y); acc[3] += bf2f_hi(sv.y);
    acc[4] += bf2f_lo(sv.z); acc[5] += bf2f_hi(sv.z);
    acc[6] += bf2f_lo(sv.w); acc[7] += bf2f_hi(sv.w);
    if (g == 0) {
        float* o = out + (size_t)n * OUT_F + (f << 3);
        *reinterpret_cast<float4*>(o)     = make_float4(acc[0], acc[1], acc[2], acc[3]);
        *reinterpret_cast<float4*>(o + 4) = make_float4(acc[4], acc[5], acc[6], acc[7]);
    }
}

extern "C" void kernel_launch(void* const* d_in, const int* in_sizes, int n_in,
                              void* d_out, int out_size, void* d_ws, size_t ws_size,
                              hipStream_t stream) {
    const float* x  = (const float*)d_in[0];
    const int* esrc = (const int*)d_in[1];
    const int* edst = (const int*)d_in[2];
    const float* W1 = (const float*)d_in[3];
    const float* W2 = (const float*)d_in[4];
    float* out      = (float*)d_out;

    const int nNodes = in_sizes[0] / IN_F;
    const int nEdges = in_sizes[1];
    const int NB = (nNodes + BUCKET_SZ - 1) / BUCKET_SZ;   // 196 (must be <= 256)
    const int A  = (nEdges + EPB - 1) / EPB;               // 196 binning blocks

    // Workspace (~84 MB; 110.4 MB known-safe). No aliasing: mlp_fused
    // reads agg and writes z concurrently across blocks.
    char* ws = (char*)d_ws;
    const size_t xb_b     = (size_t)nNodes * IN_F * sizeof(unsigned short);   // 25.6 MB
    const size_t agg_b    = (size_t)nNodes * IN_F * sizeof(unsigned short);   // 25.6 MB
    const size_t z_b      = (size_t)nNodes * OUT_F * sizeof(unsigned short);  // 12.8 MB
    const size_t binned_b = (size_t)nEdges * sizeof(unsigned long long);      // 12.8 MB
    const size_t eidx_b   = (size_t)nEdges * sizeof(int);                     //  6.4 MB
    unsigned short* xb  = (unsigned short*)ws;
    unsigned short* agg = (unsigned short*)(ws + xb_b);
    unsigned short* z   = (unsigned short*)(ws + xb_b + agg_b);
    unsigned long long* binned = (unsigned long long*)(ws + xb_b + agg_b + z_b);
    int* eidx           = (int*)(ws + xb_b + agg_b + z_b + binned_b);
    unsigned short* w1s = (unsigned short*)(ws + xb_b + agg_b + z_b + binned_b + eidx_b);
    unsigned short* w2s = w1s + IN_F * HID_F;
    int* rowptr     = (int*)(w2s + HID_F * OUT_F);
    int* counts     = rowptr + (nNodes + 1);
    int* bucketBase = counts + (size_t)NB * A;
    int* btot       = bucketBase + (NB + 1);

    k_wconv<<<(IN_F * HID_F + 255) / 256, 256, 0, stream>>>(W1, W2, w1s, w2s);

    long long total8 = (long long)nNodes * IN_F / 8;
    k_xconv<<<(int)((total8 + 255) / 256), 256, 0, stream>>>(x, xb, total8);

    k_hist<<<A, 256, 0, stream>>>(edst, counts, nEdges, NB);
    k_btot<<<NB, 256, 0, stream>>>(counts, btot, A);
    k_scanNB<<<1, 256, 0, stream>>>(btot, bucketBase, rowptr, NB, nNodes, nEdges);
    k_cursor<<<NB, 256, 0, stream>>>(counts, bucketBase, A);
    k_bin<<<A, 256, 0, stream>>>(esrc, edst, counts, binned, nEdges, NB);
    k_localcsr<<<NB, 256, 0, stream>>>(binned, bucketBase, rowptr, eidx, nNodes);

    const int nBlocks = (nNodes + 3) / 4;
    const int mBlocks = (nNodes + 63) / 64;
    gather1<<<nBlocks, 256, 0, stream>>>(xb, rowptr, eidx, agg, nNodes);
    mlp_fused<<<mBlocks, 256, 0, stream>>>(agg, w1s, w2s, z, nNodes);
    gather2<<<nBlocks, 256, 0, stream>>>(z, rowptr, eidx, out, nNodes);
}